// Round 1
// baseline (1120.785 us; speedup 1.0000x reference)
//
#include <hip/hip_runtime.h>
#include <stdint.h>
#include <stddef.h>

// Problem: out = x @ base_kernel + bias + 2.0 * (x @ kron(lora_A@lora_B, O))
// Folded:  out = x @ (base_kernel + 2.0*kron(A@B, O)) + bias  -- ONE bf16 GEMM.
// x: (16384 x 4096) f32, W: (4096 x 4096) f32, out f32.

#define M_TOT 16384
#define K_TOT 4096
#define N_TOT 4096
#define SCALING 2.0f

typedef __attribute__((ext_vector_type(8))) short bf16x8;   // 8 bf16 = 4 VGPRs (MFMA A/B frag)
typedef __attribute__((ext_vector_type(4))) float floatx4;  // MFMA C/D frag

__device__ __forceinline__ unsigned short f32_to_bf16(float f) {
  union { float f; unsigned int u; } v; v.f = f;
  unsigned int r = 0x7fffu + ((v.u >> 16) & 1u);  // round-to-nearest-even
  return (unsigned short)((v.u + r) >> 16);
}

// 16-byte async global->LDS copy (global_load_lds_dwordx4).
// HW semantics: LDS dest = wave-uniform base + lane*16 -- layout below honors this.
__device__ __forceinline__ void async_copy16(const void* gsrc, void* ldst) {
  __builtin_amdgcn_global_load_lds(
      (const __attribute__((address_space(1))) void*)(uintptr_t)gsrc,
      (__attribute__((address_space(3))) void*)(uintptr_t)ldst,
      16, 0, 0);
}

// ---- Kernel 1: wl = SCALING * (lora_A @ lora_B), 16x16, fp32 ----
__global__ void wleft_kernel(const float* __restrict__ A, const float* __restrict__ B,
                             float* __restrict__ wl) {
  int i = threadIdx.x >> 4, j = threadIdx.x & 15;
  float s = 0.f;
#pragma unroll
  for (int k = 0; k < 16; ++k) s += A[i * 16 + k] * B[k * 16 + j];
  wl[threadIdx.x] = s * SCALING;
}

// ---- Kernel 2: Wt[n][k] = bf16( base[k][n] + wl[k>>8][n>>8] * O[k&255][n&255] ) ----
// Transposed (N x K) so GEMM B-operand is K-contiguous. LDS-tiled transpose, 32x32 tiles.
__global__ void prep_w_kernel(const float* __restrict__ base, const float* __restrict__ O,
                              const float* __restrict__ wl, unsigned short* __restrict__ Wt) {
  __shared__ float tile[32][33];  // +1 pad: bank-conflict-free transpose
  int n0 = blockIdx.x * 32, k0 = blockIdx.y * 32;
  int tx = threadIdx.x, ty = threadIdx.y;  // (32, 8)
#pragma unroll
  for (int r = 0; r < 32; r += 8) {
    int k = k0 + ty + r, n = n0 + tx;
    float v = base[(size_t)k * N_TOT + n]
            + wl[((k >> 8) << 4) + (n >> 8)] * O[((size_t)(k & 255) << 8) + (n & 255)];
    tile[ty + r][tx] = v;
  }
  __syncthreads();
#pragma unroll
  for (int r = 0; r < 32; r += 8) {
    int n = n0 + ty + r, k = k0 + tx;
    Wt[(size_t)n * K_TOT + k] = f32_to_bf16(tile[tx][ty + r]);
  }
}

// ---- Kernel 3: x f32 -> bf16, 8 elems/thread ----
__global__ void cvt_x_kernel(const float* __restrict__ x, unsigned short* __restrict__ xb) {
  size_t i = ((size_t)blockIdx.x * blockDim.x + threadIdx.x) * 8;
  float4 a = *(const float4*)(x + i);
  float4 b = *(const float4*)(x + i + 4);
  union { bf16x8 v; unsigned short h[8]; } u;
  u.h[0] = f32_to_bf16(a.x); u.h[1] = f32_to_bf16(a.y);
  u.h[2] = f32_to_bf16(a.z); u.h[3] = f32_to_bf16(a.w);
  u.h[4] = f32_to_bf16(b.x); u.h[5] = f32_to_bf16(b.y);
  u.h[6] = f32_to_bf16(b.z); u.h[7] = f32_to_bf16(b.w);
  *(bf16x8*)(xb + i) = u.v;
}

// ---- Kernel 4: C = Xb(M x K) @ Wt(N x K)^T + bias, bf16 MFMA, fp32 out ----
// 128x128 block tile, BK=32, 4 waves in 2x2, each wave 64x64 = 4x4 mfma_f32_16x16x32_bf16.
__global__ __launch_bounds__(256) void gemm_bt_kernel(
    const unsigned short* __restrict__ Xb, const unsigned short* __restrict__ Wt,
    const float* __restrict__ bias, float* __restrict__ out) {
  // Unpadded: global_load_lds lands lane i at base + i*16 -- layout must be linear.
  __shared__ __align__(16) unsigned short Alds[128 * 32];
  __shared__ __align__(16) unsigned short Blds[128 * 32];

  const int tid = threadIdx.x;
  const int wave = tid >> 6, lane = tid & 63;
  const int quad = lane >> 4, lanemod = lane & 15;
  const int wm = wave & 1, wn = wave >> 1;

  const int m0 = blockIdx.y * 128, n0 = blockIdx.x * 128;

  floatx4 acc[4][4];
#pragma unroll
  for (int i = 0; i < 4; ++i)
#pragma unroll
    for (int j = 0; j < 4; ++j) acc[i][j] = (floatx4){0.f, 0.f, 0.f, 0.f};

  for (int k0 = 0; k0 < K_TOT; k0 += 32) {
    // Stage 128x32 bf16 A-tile and B-tile: 512 chunks of 16B each, 2 iters x 256 threads.
    // chunk c: row = c/4 (0..127), kchunk = c%4 (8 bf16 each). LDS linear offset = c*16B.
#pragma unroll
    for (int it = 0; it < 2; ++it) {
      int c = it * 256 + tid;
      int row = c >> 2, kc = c & 3;
      async_copy16(Xb + ((size_t)(m0 + row) * K_TOT + k0 + kc * 8), Alds + (size_t)c * 8);
      async_copy16(Wt + ((size_t)(n0 + row) * K_TOT + k0 + kc * 8), Blds + (size_t)c * 8);
    }
    __syncthreads();  // compiler emits vmcnt(0) drain before s_barrier

    bf16x8 af[4], bfr[4];
#pragma unroll
    for (int t = 0; t < 4; ++t) {
      // A-operand: lane holds A[m=lanemod][k = quad*8 + j] -> contiguous 16B in LDS row
      af[t]  = *(const bf16x8*)(Alds + ((wm * 64 + t * 16 + lanemod) * 32 + quad * 8));
      bfr[t] = *(const bf16x8*)(Blds + ((wn * 64 + t * 16 + lanemod) * 32 + quad * 8));
    }
#pragma unroll
    for (int mt = 0; mt < 4; ++mt)
#pragma unroll
      for (int nt = 0; nt < 4; ++nt)
        acc[mt][nt] = __builtin_amdgcn_mfma_f32_16x16x32_bf16(af[mt], bfr[nt], acc[mt][nt], 0, 0, 0);
    __syncthreads();
  }

  // Epilogue: C/D layout col = lane&15, row = quad*4 + reg. Fuse bias.
#pragma unroll
  for (int nt = 0; nt < 4; ++nt) {
    int col = n0 + wn * 64 + nt * 16 + lanemod;
    float bv = bias[col];
#pragma unroll
    for (int mt = 0; mt < 4; ++mt) {
      int row = m0 + wm * 64 + mt * 16 + quad * 4;
#pragma unroll
      for (int r = 0; r < 4; ++r)
        out[(size_t)(row + r) * N_TOT + col] = acc[mt][nt][r] + bv;
    }
  }
}

extern "C" void kernel_launch(void* const* d_in, const int* in_sizes, int n_in,
                              void* d_out, int out_size, void* d_ws, size_t ws_size,
                              hipStream_t stream) {
  const float* x    = (const float*)d_in[0];  // (4,4096,4096) -> M=16384, K=4096
  const float* base = (const float*)d_in[1];  // (4096,4096) K x N
  const float* bias = (const float*)d_in[2];  // (4096,)
  const float* lA   = (const float*)d_in[3];  // (16,16)
  const float* lB   = (const float*)d_in[4];  // (16,16)
  const float* O    = (const float*)d_in[5];  // (256,256)
  float* out = (float*)d_out;

  // Workspace layout: Xb bf16 (128 MB) | Wt bf16 (32 MB) | wl f32 (1 KB)
  char* ws = (char*)d_ws;
  unsigned short* Xb = (unsigned short*)ws;
  unsigned short* Wt = (unsigned short*)(ws + (size_t)M_TOT * K_TOT * 2);
  float* wl = (float*)(ws + (size_t)M_TOT * K_TOT * 2 + (size_t)N_TOT * K_TOT * 2);

  wleft_kernel<<<1, 256, 0, stream>>>(lA, lB, wl);
  prep_w_kernel<<<dim3(N_TOT / 32, K_TOT / 32), dim3(32, 8), 0, stream>>>(base, O, wl, Wt);
  cvt_x_kernel<<<((size_t)M_TOT * K_TOT) / 8 / 256, 256, 0, stream>>>(x, Xb);
  gemm_bt_kernel<<<dim3(N_TOT / 128, M_TOT / 128), 256, 0, stream>>>(Xb, Wt, bias, out);
}